// Round 11
// baseline (158.021 us; speedup 1.0000x reference)
//
#include <hip/hip_runtime.h>
#include <hip/hip_fp16.h>
#include <math.h>

// MultiHeadAttentionQuantum: analytic collapse of the 8-qubit circuit.
//   angles[t][n] = dot(x[t], w_q[n]) + q_params[n] ; c = cos(angles)
//   z[0] = c1..c7 ; z[w>=1] = c0..cw  (Heisenberg CNOT-ring push-through)
//   out[t][e] = sum_n z[n] * w_out[e][n]
//
// R11: R8/R10 pinned at ~37us = 4.0 TB/s effective (63% of copy ceiling).
// Per-wave load duty ~25%; 48 KB LDS caps 3 blocks/CU -> 12 waves/CU, too
// few staggered waves to keep HBM reads continuous. This round: weights in
// LDS as FP16 (24 KB -> 6 blocks/CU = 24 waves/CU), math stays fp32
// (cvt on read; weight quant error ~1e-3 << 0.058 threshold). 2 tok/wave x
// 2 groups (16 tok/block, grid 2048 = same staging traffic as R8); group-1
// x loads issued after group-0 dot (xv0 dead -> register-neutral overlap);
// epilogue n-split to keep VGPR <= 85 (bounds(256,6), no spill).

using f32x4 = __attribute__((ext_vector_type(4))) float;

constexpr int E  = 768;
constexpr int NW = 8;
constexpr int BLOCK = 256;                                // 4 waves
constexpr int TOKENS = 16 * 2048;                         // 32768
constexpr int TOK_PER_WAVE  = 2;                          // per group
constexpr int GROUPS = 2;
constexpr int TOK_PER_BLOCK = TOK_PER_WAVE * 4 * GROUPS;  // 16
constexpr int GRID = TOKENS / TOK_PER_BLOCK;              // 2048

// Wave-wide reduce of zf[0..7] + cos + CNOT-ring prefix products.
// Numerically verified R4-R10 (absmax 0.0078).
__device__ __forceinline__ void circuit8(const float zf[NW], int lane, float qpl,
                                         float z[NW]) {
    float v4[4];
    #pragma unroll
    for (int i = 0; i < 4; ++i) {
        float a = zf[2*i], b = zf[2*i+1];
        float keep = (lane & 1) ? b : a;
        float send = (lane & 1) ? a : b;
        v4[i] = keep + __shfl_xor(send, 1, 64);
    }
    float v2[2];
    #pragma unroll
    for (int i = 0; i < 2; ++i) {
        float a = v4[2*i], b = v4[2*i+1];
        float keep = (lane & 2) ? b : a;
        float send = (lane & 2) ? a : b;
        v2[i] = keep + __shfl_xor(send, 2, 64);
    }
    float a = v2[0], b = v2[1];
    float keep = (lane & 4) ? b : a;
    float send = (lane & 4) ? a : b;
    float v = keep + __shfl_xor(send, 4, 64);
    v += __shfl_xor(v, 8, 64);
    v += __shfl_xor(v, 16, 64);
    v += __shfl_xor(v, 32, 64);
    float c = __cosf(v + qpl);               // one cos per token (wire lane&7)
    float cx = __shfl_xor(c, 1, 64);
    float e0 = (lane & 1) ? cx : c;
    float e1 = (lane & 1) ? c : cx;
    float e0x = __shfl_xor(e0, 2, 64), e1x = __shfl_xor(e1, 2, 64);
    float f0 = (lane & 2) ? e0x : e0;
    float f1 = (lane & 2) ? e1x : e1;
    float f2 = (lane & 2) ? e0  : e0x;
    float f3 = (lane & 2) ? e1  : e1x;
    float f0x = __shfl_xor(f0, 4, 64), f1x = __shfl_xor(f1, 4, 64);
    float f2x = __shfl_xor(f2, 4, 64), f3x = __shfl_xor(f3, 4, 64);
    float c0 = (lane & 4) ? f0x : f0;
    float c1 = (lane & 4) ? f1x : f1;
    float c2 = (lane & 4) ? f2x : f2;
    float c3 = (lane & 4) ? f3x : f3;
    float c4 = (lane & 4) ? f0  : f0x;
    float c5 = (lane & 4) ? f1  : f1x;
    float c6 = (lane & 4) ? f2  : f2x;
    float c7 = (lane & 4) ? f3  : f3x;
    float p1 = c0*c1, p2 = p1*c2, p3 = p2*c3, p4 = p3*c4;
    float p5 = p4*c5, p6 = p5*c6, p7 = p6*c7;
    float s  = c1*c2*c3*c4*c5*c6*c7;
    z[0] = s;  z[1] = p1; z[2] = p2; z[3] = p3;
    z[4] = p4; z[5] = p5; z[6] = p6; z[7] = p7;
}

__device__ __forceinline__ void load_x2(const float* __restrict__ x, int t0, int lane,
                                        f32x4 xv[TOK_PER_WAVE][3]) {
    #pragma unroll
    for (int tt = 0; tt < TOK_PER_WAVE; ++tt) {
        const f32x4* xp = reinterpret_cast<const f32x4*>(x + (size_t)(t0 + tt) * E);
        #pragma unroll
        for (int k = 0; k < 3; ++k)
            xv[tt][k] = xp[lane + k * 64];
    }
}

__device__ __forceinline__ void dot_phase2(const f32x4 xv[TOK_PER_WAVE][3],
                                           const __half (*wq)[E], int col,
                                           float zf[TOK_PER_WAVE][NW]) {
    #pragma unroll
    for (int n = 0; n < NW; ++n) {
        const __half2* wp = reinterpret_cast<const __half2*>(&wq[n][col]);
        // chunks at elements +0, +256, +512 -> half2 offsets 0/1, 128/129, 256/257
        float2 w0a = __half22float2(wp[0]);
        float2 w0b = __half22float2(wp[1]);
        float2 w1a = __half22float2(wp[128]);
        float2 w1b = __half22float2(wp[129]);
        float2 w2a = __half22float2(wp[256]);
        float2 w2b = __half22float2(wp[257]);
        #pragma unroll
        for (int tt = 0; tt < TOK_PER_WAVE; ++tt) {
            zf[tt][n] =
                  xv[tt][0].x*w0a.x + xv[tt][0].y*w0a.y + xv[tt][0].z*w0b.x + xv[tt][0].w*w0b.y
                + xv[tt][1].x*w1a.x + xv[tt][1].y*w1a.y + xv[tt][1].z*w1b.x + xv[tt][1].w*w1b.y
                + xv[tt][2].x*w2a.x + xv[tt][2].y*w2a.y + xv[tt][2].z*w2b.x + xv[tt][2].w*w2b.y;
        }
    }
}

__device__ __forceinline__ void finish_phase2(float zf[TOK_PER_WAVE][NW],
                                              const __half (*wt)[E],
                                              int t0, int lane, int col, float qpl,
                                              float* __restrict__ out) {
    float z[TOK_PER_WAVE][NW];
    #pragma unroll
    for (int tt = 0; tt < TOK_PER_WAVE; ++tt)
        circuit8(zf[tt], lane, qpl, z[tt]);

    #pragma unroll
    for (int k = 0; k < 3; ++k) {
        const int e0 = k * 256 + col;       // this lane's 4 output columns
        f32x4 o[TOK_PER_WAVE];
        #pragma unroll
        for (int tt = 0; tt < TOK_PER_WAVE; ++tt) { o[tt].x = o[tt].y = o[tt].z = o[tt].w = 0.f; }
        // n in halves of 4 to bound live registers
        #pragma unroll
        for (int h = 0; h < 2; ++h) {
            #pragma unroll
            for (int n4 = 0; n4 < 4; ++n4) {
                const int n = h * 4 + n4;
                const __half2* hp = reinterpret_cast<const __half2*>(&wt[n][e0]);
                float2 fa = __half22float2(hp[0]);
                float2 fb = __half22float2(hp[1]);
                #pragma unroll
                for (int tt = 0; tt < TOK_PER_WAVE; ++tt) {
                    o[tt].x += z[tt][n] * fa.x;
                    o[tt].y += z[tt][n] * fa.y;
                    o[tt].z += z[tt][n] * fb.x;
                    o[tt].w += z[tt][n] * fb.y;
                }
            }
        }
        #pragma unroll
        for (int tt = 0; tt < TOK_PER_WAVE; ++tt)
            __builtin_nontemporal_store(
                o[tt], reinterpret_cast<f32x4*>(out + (size_t)(t0 + tt) * E + e0));
    }
}

__global__ __launch_bounds__(BLOCK, 6)
void mhaq_kernel(const float* __restrict__ x,
                 const float* __restrict__ w_q,
                 const float* __restrict__ w_out,
                 const float* __restrict__ q_params,
                 float* __restrict__ out)
{
    __shared__ __align__(16) __half wq_lds[NW][E];   // 12 KB, w_q as-is [n][e], fp16
    __shared__ __align__(16) __half wt_lds[NW][E];   // 12 KB, w_out transposed [n][e], fp16

    const int tid  = threadIdx.x;
    const int wave = tid >> 6;
    const int lane = tid & 63;
    const int col  = lane * 4;
    const int t0a  = blockIdx.x * TOK_PER_BLOCK + wave * TOK_PER_WAVE;   // group 0
    const int t0b  = t0a + TOK_PER_WAVE * 4;                             // group 1

    // ---- group-0 x loads first: HBM latency overlaps staging ----
    f32x4 xv0[TOK_PER_WAVE][3];
    load_x2(x, t0a, lane, xv0);

    // ---- stage weights once per block, fp32 -> fp16 ----
    {
        const f32x4* src = reinterpret_cast<const f32x4*>(w_q);
        __half2* dst = reinterpret_cast<__half2*>(&wq_lds[0][0]);
        #pragma unroll
        for (int r = 0; r < (NW * E / 4) / BLOCK; ++r) {
            int idx = tid + r * BLOCK;
            f32x4 v = src[idx];
            dst[idx * 2]     = __floats2half2_rn(v.x, v.y);
            dst[idx * 2 + 1] = __floats2half2_rn(v.z, v.w);
        }
    }
    {
        const f32x4* src = reinterpret_cast<const f32x4*>(w_out);
        #pragma unroll
        for (int r = 0; r < (NW * E / 4) / BLOCK; ++r) {
            int idx = tid + r * BLOCK;       // f32x4 index into [768][8]
            f32x4 v = src[idx];
            int e  = idx >> 1;               // two f32x4 per e-row
            int n0 = (idx & 1) * 4;
            wt_lds[n0 + 0][e] = __float2half(v.x);
            wt_lds[n0 + 1][e] = __float2half(v.y);
            wt_lds[n0 + 2][e] = __float2half(v.z);
            wt_lds[n0 + 3][e] = __float2half(v.w);
        }
    }
    const float qpl = q_params[lane & 7];
    __syncthreads();

    // ---- group 0: dot, then issue group-1 loads (xv0 dead -> reg-neutral) ----
    float zf0[TOK_PER_WAVE][NW];
    dot_phase2(xv0, wq_lds, col, zf0);

    f32x4 xv1[TOK_PER_WAVE][3];
    load_x2(x, t0b, lane, xv1);              // latency hidden under finish_phase(0)

    finish_phase2(zf0, wt_lds, t0a, lane, col, qpl, out);

    // ---- group 1 ----
    float zf1[TOK_PER_WAVE][NW];
    dot_phase2(xv1, wq_lds, col, zf1);
    finish_phase2(zf1, wt_lds, t0b, lane, col, qpl, out);
}

extern "C" void kernel_launch(void* const* d_in, const int* in_sizes, int n_in,
                              void* d_out, int out_size, void* d_ws, size_t ws_size,
                              hipStream_t stream) {
    const float* x        = (const float*)d_in[0];
    const float* w_q      = (const float*)d_in[1];
    const float* w_out    = (const float*)d_in[2];
    const float* q_params = (const float*)d_in[3];
    float* out = (float*)d_out;

    hipLaunchKernelGGL(mhaq_kernel, dim3(GRID), dim3(BLOCK), 0, stream,
                       x, w_q, w_out, q_params, out);
}

// Round 12
// 45.273 us; speedup vs baseline: 3.4904x; 3.4904x over previous
//
#include <hip/hip_runtime.h>
#include <math.h>

// MultiHeadAttentionQuantum: analytic collapse of the 8-qubit circuit.
//   angles[t][n] = dot(x[t], w_q[n]) + q_params[n] ; c = cos(angles)
//   z[0] = c1..c7 ; z[w>=1] = c0..cw  (Heisenberg CNOT-ring push-through)
//   out[t][e] = sum_n z[n] * w_out[e][n]
//
// R12: R11's bounds(256,6) squeezed VGPR to 40 -> 294 MB of spill (3rd
// spill incident; rule: ONLY bounds(.,4)). R8 (37.2us) structure is right;
// its 12 waves/CU came from 48KB LDS x 256-thread blocks. This round:
// BLOCK=512 (8 waves) -> same 3 blocks/CU but 24 waves/CU, staging traffic
// halved (1024 x 48KB). Per-wave work, registers, numerics IDENTICAL to R8.

using f32x4 = __attribute__((ext_vector_type(4))) float;

constexpr int E  = 768;
constexpr int NW = 8;
constexpr int BLOCK = 512;                      // 8 waves
constexpr int TOKENS = 16 * 2048;               // 32768
constexpr int TOK_PER_WAVE  = 4;
constexpr int TOK_PER_BLOCK = TOK_PER_WAVE * 8; // 32
constexpr int GRID = TOKENS / TOK_PER_BLOCK;    // 1024

__device__ __forceinline__ float dot12(const f32x4& a0, const f32x4& a1, const f32x4& a2,
                                       const f32x4& b0, const f32x4& b1, const f32x4& b2) {
    return a0.x*b0.x + a0.y*b0.y + a0.z*b0.z + a0.w*b0.w
         + a1.x*b1.x + a1.y*b1.y + a1.z*b1.z + a1.w*b1.w
         + a2.x*b2.x + a2.y*b2.y + a2.z*b2.z + a2.w*b2.w;
}

// Wave-wide reduce of zf[0..7] + cos + CNOT-ring prefix products.
// Numerically verified R4-R10 (absmax 0.0078).
__device__ __forceinline__ void circuit8(const float zf[NW], int lane, float qpl,
                                         float z[NW]) {
    float v4[4];
    #pragma unroll
    for (int i = 0; i < 4; ++i) {
        float a = zf[2*i], b = zf[2*i+1];
        float keep = (lane & 1) ? b : a;
        float send = (lane & 1) ? a : b;
        v4[i] = keep + __shfl_xor(send, 1, 64);
    }
    float v2[2];
    #pragma unroll
    for (int i = 0; i < 2; ++i) {
        float a = v4[2*i], b = v4[2*i+1];
        float keep = (lane & 2) ? b : a;
        float send = (lane & 2) ? a : b;
        v2[i] = keep + __shfl_xor(send, 2, 64);
    }
    float a = v2[0], b = v2[1];
    float keep = (lane & 4) ? b : a;
    float send = (lane & 4) ? a : b;
    float v = keep + __shfl_xor(send, 4, 64);
    v += __shfl_xor(v, 8, 64);
    v += __shfl_xor(v, 16, 64);
    v += __shfl_xor(v, 32, 64);
    float c = __cosf(v + qpl);               // one cos per token (wire lane&7)
    float cx = __shfl_xor(c, 1, 64);
    float e0 = (lane & 1) ? cx : c;
    float e1 = (lane & 1) ? c : cx;
    float e0x = __shfl_xor(e0, 2, 64), e1x = __shfl_xor(e1, 2, 64);
    float f0 = (lane & 2) ? e0x : e0;
    float f1 = (lane & 2) ? e1x : e1;
    float f2 = (lane & 2) ? e0  : e0x;
    float f3 = (lane & 2) ? e1  : e1x;
    float f0x = __shfl_xor(f0, 4, 64), f1x = __shfl_xor(f1, 4, 64);
    float f2x = __shfl_xor(f2, 4, 64), f3x = __shfl_xor(f3, 4, 64);
    float c0 = (lane & 4) ? f0x : f0;
    float c1 = (lane & 4) ? f1x : f1;
    float c2 = (lane & 4) ? f2x : f2;
    float c3 = (lane & 4) ? f3x : f3;
    float c4 = (lane & 4) ? f0  : f0x;
    float c5 = (lane & 4) ? f1  : f1x;
    float c6 = (lane & 4) ? f2  : f2x;
    float c7 = (lane & 4) ? f3  : f3x;
    float p1 = c0*c1, p2 = p1*c2, p3 = p2*c3, p4 = p3*c4;
    float p5 = p4*c5, p6 = p5*c6, p7 = p6*c7;
    float s  = c1*c2*c3*c4*c5*c6*c7;
    z[0] = s;  z[1] = p1; z[2] = p2; z[3] = p3;
    z[4] = p4; z[5] = p5; z[6] = p6; z[7] = p7;
}

__global__ __launch_bounds__(BLOCK, 4)
void mhaq_kernel(const float* __restrict__ x,
                 const float* __restrict__ w_q,
                 const float* __restrict__ w_out,
                 const float* __restrict__ q_params,
                 float* __restrict__ out)
{
    __shared__ float wq_lds[NW][E];   // 24 KB, w_q as-is [n][e]
    __shared__ float wt_lds[NW][E];   // 24 KB, w_out transposed [n][e]

    const int tid  = threadIdx.x;
    const int wave = tid >> 6;
    const int lane = tid & 63;
    const int col  = lane * 4;
    const int t0   = blockIdx.x * TOK_PER_BLOCK + wave * TOK_PER_WAVE;

    // ---- x loads issued FIRST: HBM latency overlaps (L2-hit) staging ----
    f32x4 xv[TOK_PER_WAVE][3];
    #pragma unroll
    for (int tt = 0; tt < TOK_PER_WAVE; ++tt) {
        const f32x4* xp = reinterpret_cast<const f32x4*>(x + (size_t)(t0 + tt) * E);
        #pragma unroll
        for (int k = 0; k < 3; ++k)
            xv[tt][k] = xp[lane + k * 64];
    }

    // ---- stage weights once per block (3 f32x4 per thread each) ----
    {
        const f32x4* src = reinterpret_cast<const f32x4*>(w_q);
        f32x4* dst = reinterpret_cast<f32x4*>(&wq_lds[0][0]);
        #pragma unroll
        for (int r = 0; r < (NW * E / 4) / BLOCK; ++r)
            dst[tid + r * BLOCK] = src[tid + r * BLOCK];
    }
    {
        const f32x4* src = reinterpret_cast<const f32x4*>(w_out);
        #pragma unroll
        for (int r = 0; r < (NW * E / 4) / BLOCK; ++r) {
            int idx = tid + r * BLOCK;       // f32x4 index into [768][8]
            f32x4 v = src[idx];
            int e  = idx >> 1;               // two f32x4 per e-row
            int n0 = (idx & 1) * 4;
            wt_lds[n0 + 0][e] = v.x;
            wt_lds[n0 + 1][e] = v.y;
            wt_lds[n0 + 2][e] = v.z;
            wt_lds[n0 + 3][e] = v.w;
        }
    }
    const float qpl = q_params[lane & 7];
    __syncthreads();

    // ---- per-lane partial dots (w_q from LDS) ----
    float zf[TOK_PER_WAVE][NW];
    #pragma unroll
    for (int n = 0; n < NW; ++n) {
        const f32x4 w0 = *reinterpret_cast<const f32x4*>(&wq_lds[n][col]);
        const f32x4 w1 = *reinterpret_cast<const f32x4*>(&wq_lds[n][col + 256]);
        const f32x4 w2 = *reinterpret_cast<const f32x4*>(&wq_lds[n][col + 512]);
        #pragma unroll
        for (int tt = 0; tt < TOK_PER_WAVE; ++tt)
            zf[tt][n] = dot12(xv[tt][0], xv[tt][1], xv[tt][2], w0, w1, w2);
    }

    // ---- wave reduce + cos + prefix products ----
    float z[TOK_PER_WAVE][NW];
    #pragma unroll
    for (int tt = 0; tt < TOK_PER_WAVE; ++tt)
        circuit8(zf[tt], lane, qpl, z[tt]);

    // ---- epilogue: out[t][e] = sum_n z[n] * w_out[e][n] (w_out from LDS) ----
    #pragma unroll
    for (int k = 0; k < 3; ++k) {
        const int e0 = k * 256 + col;
        f32x4 wv[NW];
        #pragma unroll
        for (int n = 0; n < NW; ++n)
            wv[n] = *reinterpret_cast<const f32x4*>(&wt_lds[n][e0]);
        #pragma unroll
        for (int tt = 0; tt < TOK_PER_WAVE; ++tt) {
            float ox = 0.f, oy = 0.f, oz = 0.f, ow = 0.f;
            #pragma unroll
            for (int n = 0; n < NW; ++n) {
                ox += z[tt][n] * wv[n].x;
                oy += z[tt][n] * wv[n].y;
                oz += z[tt][n] * wv[n].z;
                ow += z[tt][n] * wv[n].w;
            }
            f32x4 o; o.x = ox; o.y = oy; o.z = oz; o.w = ow;
            __builtin_nontemporal_store(
                o, reinterpret_cast<f32x4*>(out + (size_t)(t0 + tt) * E + e0));
        }
    }
}

extern "C" void kernel_launch(void* const* d_in, const int* in_sizes, int n_in,
                              void* d_out, int out_size, void* d_ws, size_t ws_size,
                              hipStream_t stream) {
    const float* x        = (const float*)d_in[0];
    const float* w_q      = (const float*)d_in[1];
    const float* w_out    = (const float*)d_in[2];
    const float* q_params = (const float*)d_in[3];
    float* out = (float*)d_out;

    hipLaunchKernelGGL(mhaq_kernel, dim3(GRID), dim3(BLOCK), 0, stream,
                       x, w_q, w_out, q_params, out);
}

// Round 13
// 36.107 us; speedup vs baseline: 4.3764x; 1.2538x over previous
//
#include <hip/hip_runtime.h>
#include <math.h>

// MultiHeadAttentionQuantum: analytic collapse of the 8-qubit circuit.
//   angles[t][n] = dot(x[t], w_q[n]) + q_params[n] ; c = cos(angles)
//   z[0] = c1..c7 ; z[w>=1] = c0..cw  (Heisenberg CNOT-ring push-through)
//   out[t][e] = sum_n z[n] * w_out[e][n]
//
// R13: occupancy lever exhausted (R7/R9/R11/R12 all lost to spill or global
// weight re-reads; rule: bounds(.,4) only, all weights in LDS, BLOCK=256).
// R8 = 37.2us at 63% HBM duty. Single-variable probe: nontemporal stores ->
// PLAIN caching stores (fill kernel proves plain stores sustain 7 TB/s via
// L2/L3 write-allocate + lazy writeback; nt was never isolated on R8).
// Everything else byte-identical to R8.

using f32x4 = __attribute__((ext_vector_type(4))) float;

constexpr int E  = 768;
constexpr int NW = 8;
constexpr int BLOCK = 256;                      // 4 waves
constexpr int TOKENS = 16 * 2048;               // 32768
constexpr int TOK_PER_WAVE  = 4;
constexpr int TOK_PER_BLOCK = TOK_PER_WAVE * 4; // 16
constexpr int GRID = TOKENS / TOK_PER_BLOCK;    // 2048

__device__ __forceinline__ float dot12(const f32x4& a0, const f32x4& a1, const f32x4& a2,
                                       const f32x4& b0, const f32x4& b1, const f32x4& b2) {
    return a0.x*b0.x + a0.y*b0.y + a0.z*b0.z + a0.w*b0.w
         + a1.x*b1.x + a1.y*b1.y + a1.z*b1.z + a1.w*b1.w
         + a2.x*b2.x + a2.y*b2.y + a2.z*b2.z + a2.w*b2.w;
}

// Wave-wide reduce of zf[0..7] + cos + CNOT-ring prefix products.
// Numerically verified R4-R12 (absmax 0.0078).
__device__ __forceinline__ void circuit8(const float zf[NW], int lane, float qpl,
                                         float z[NW]) {
    float v4[4];
    #pragma unroll
    for (int i = 0; i < 4; ++i) {
        float a = zf[2*i], b = zf[2*i+1];
        float keep = (lane & 1) ? b : a;
        float send = (lane & 1) ? a : b;
        v4[i] = keep + __shfl_xor(send, 1, 64);
    }
    float v2[2];
    #pragma unroll
    for (int i = 0; i < 2; ++i) {
        float a = v4[2*i], b = v4[2*i+1];
        float keep = (lane & 2) ? b : a;
        float send = (lane & 2) ? a : b;
        v2[i] = keep + __shfl_xor(send, 2, 64);
    }
    float a = v2[0], b = v2[1];
    float keep = (lane & 4) ? b : a;
    float send = (lane & 4) ? a : b;
    float v = keep + __shfl_xor(send, 4, 64);
    v += __shfl_xor(v, 8, 64);
    v += __shfl_xor(v, 16, 64);
    v += __shfl_xor(v, 32, 64);
    float c = __cosf(v + qpl);               // one cos per token (wire lane&7)
    float cx = __shfl_xor(c, 1, 64);
    float e0 = (lane & 1) ? cx : c;
    float e1 = (lane & 1) ? c : cx;
    float e0x = __shfl_xor(e0, 2, 64), e1x = __shfl_xor(e1, 2, 64);
    float f0 = (lane & 2) ? e0x : e0;
    float f1 = (lane & 2) ? e1x : e1;
    float f2 = (lane & 2) ? e0  : e0x;
    float f3 = (lane & 2) ? e1  : e1x;
    float f0x = __shfl_xor(f0, 4, 64), f1x = __shfl_xor(f1, 4, 64);
    float f2x = __shfl_xor(f2, 4, 64), f3x = __shfl_xor(f3, 4, 64);
    float c0 = (lane & 4) ? f0x : f0;
    float c1 = (lane & 4) ? f1x : f1;
    float c2 = (lane & 4) ? f2x : f2;
    float c3 = (lane & 4) ? f3x : f3;
    float c4 = (lane & 4) ? f0  : f0x;
    float c5 = (lane & 4) ? f1  : f1x;
    float c6 = (lane & 4) ? f2  : f2x;
    float c7 = (lane & 4) ? f3  : f3x;
    float p1 = c0*c1, p2 = p1*c2, p3 = p2*c3, p4 = p3*c4;
    float p5 = p4*c5, p6 = p5*c6, p7 = p6*c7;
    float s  = c1*c2*c3*c4*c5*c6*c7;
    z[0] = s;  z[1] = p1; z[2] = p2; z[3] = p3;
    z[4] = p4; z[5] = p5; z[6] = p6; z[7] = p7;
}

__global__ __launch_bounds__(BLOCK, 4)
void mhaq_kernel(const float* __restrict__ x,
                 const float* __restrict__ w_q,
                 const float* __restrict__ w_out,
                 const float* __restrict__ q_params,
                 float* __restrict__ out)
{
    __shared__ float wq_lds[NW][E];   // 24 KB, w_q as-is [n][e]
    __shared__ float wt_lds[NW][E];   // 24 KB, w_out transposed [n][e]

    const int tid  = threadIdx.x;
    const int wave = tid >> 6;
    const int lane = tid & 63;
    const int col  = lane * 4;
    const int t0   = blockIdx.x * TOK_PER_BLOCK + wave * TOK_PER_WAVE;

    // ---- x loads issued FIRST: HBM latency overlaps (L2-hit) staging ----
    f32x4 xv[TOK_PER_WAVE][3];
    #pragma unroll
    for (int tt = 0; tt < TOK_PER_WAVE; ++tt) {
        const f32x4* xp = reinterpret_cast<const f32x4*>(x + (size_t)(t0 + tt) * E);
        #pragma unroll
        for (int k = 0; k < 3; ++k)
            xv[tt][k] = xp[lane + k * 64];
    }

    // ---- stage weights once per block ----
    {
        const f32x4* src = reinterpret_cast<const f32x4*>(w_q);
        f32x4* dst = reinterpret_cast<f32x4*>(&wq_lds[0][0]);
        #pragma unroll
        for (int r = 0; r < (NW * E / 4) / BLOCK; ++r)
            dst[tid + r * BLOCK] = src[tid + r * BLOCK];
    }
    {
        const f32x4* src = reinterpret_cast<const f32x4*>(w_out);
        #pragma unroll
        for (int r = 0; r < (NW * E / 4) / BLOCK; ++r) {
            int idx = tid + r * BLOCK;       // f32x4 index into [768][8]
            f32x4 v = src[idx];
            int e  = idx >> 1;               // two f32x4 per e-row
            int n0 = (idx & 1) * 4;
            wt_lds[n0 + 0][e] = v.x;
            wt_lds[n0 + 1][e] = v.y;
            wt_lds[n0 + 2][e] = v.z;
            wt_lds[n0 + 3][e] = v.w;
        }
    }
    const float qpl = q_params[lane & 7];
    __syncthreads();

    // ---- per-lane partial dots (w_q from LDS) ----
    float zf[TOK_PER_WAVE][NW];
    #pragma unroll
    for (int n = 0; n < NW; ++n) {
        const f32x4 w0 = *reinterpret_cast<const f32x4*>(&wq_lds[n][col]);
        const f32x4 w1 = *reinterpret_cast<const f32x4*>(&wq_lds[n][col + 256]);
        const f32x4 w2 = *reinterpret_cast<const f32x4*>(&wq_lds[n][col + 512]);
        #pragma unroll
        for (int tt = 0; tt < TOK_PER_WAVE; ++tt)
            zf[tt][n] = dot12(xv[tt][0], xv[tt][1], xv[tt][2], w0, w1, w2);
    }

    // ---- wave reduce + cos + prefix products ----
    float z[TOK_PER_WAVE][NW];
    #pragma unroll
    for (int tt = 0; tt < TOK_PER_WAVE; ++tt)
        circuit8(zf[tt], lane, qpl, z[tt]);

    // ---- epilogue: out[t][e] = sum_n z[n] * w_out[e][n] (w_out from LDS),
    //      PLAIN stores: write-allocate L2/L3, lazy writeback ----
    #pragma unroll
    for (int k = 0; k < 3; ++k) {
        const int e0 = k * 256 + col;
        f32x4 wv[NW];
        #pragma unroll
        for (int n = 0; n < NW; ++n)
            wv[n] = *reinterpret_cast<const f32x4*>(&wt_lds[n][e0]);
        #pragma unroll
        for (int tt = 0; tt < TOK_PER_WAVE; ++tt) {
            float ox = 0.f, oy = 0.f, oz = 0.f, ow = 0.f;
            #pragma unroll
            for (int n = 0; n < NW; ++n) {
                ox += z[tt][n] * wv[n].x;
                oy += z[tt][n] * wv[n].y;
                oz += z[tt][n] * wv[n].z;
                ow += z[tt][n] * wv[n].w;
            }
            f32x4 o; o.x = ox; o.y = oy; o.z = oz; o.w = ow;
            *reinterpret_cast<f32x4*>(out + (size_t)(t0 + tt) * E + e0) = o;
        }
    }
}

extern "C" void kernel_launch(void* const* d_in, const int* in_sizes, int n_in,
                              void* d_out, int out_size, void* d_ws, size_t ws_size,
                              hipStream_t stream) {
    const float* x        = (const float*)d_in[0];
    const float* w_q      = (const float*)d_in[1];
    const float* w_out    = (const float*)d_in[2];
    const float* q_params = (const float*)d_in[3];
    float* out = (float*)d_out;

    hipLaunchKernelGGL(mhaq_kernel, dim3(GRID), dim3(BLOCK), 0, stream,
                       x, w_q, w_out, q_params, out);
}